// Round 2
// baseline (1059.234 us; speedup 1.0000x reference)
//
#include <hip/hip_runtime.h>
#include <cfloat>

// Problem constants (match reference)
#define Hh 512
#define Ww 512
#define H1 510
#define W1 510
#define H2 508
#define W2 508
#define CIN 3
#define C1C 20
#define C2C 40
#define NACT 18
#define NFC (C2C * H2 * W2)      // 10,322,560
#define N4  (NFC / 4)            // 2,580,640 float4

#define GRID_MV   2048
#define GRID_CORR 256

// ---------------- bbox helpers ----------------
struct Box { int rx1, rx2, ry1, ry2, bx1, bx2, by1, by2; };

__device__ inline Box make_box(const int* __restrict__ bb) {
  Box b;
  int mnx = bb[0], mxx = bb[1], mny = bb[2], mxy = bb[3];
  b.rx1 = max(mnx - 2, 0);  b.rx2 = min(mxx + 3, Hh);
  b.ry1 = max(mny - 2, 0);  b.ry2 = min(mxy + 3, Ww);
  b.bx1 = max(b.rx1 - 2, 0); b.bx2 = min(min(b.rx2 + 3, Hh), H1);
  b.by1 = max(b.ry1 - 2, 0); b.by2 = min(min(b.ry2 + 3, Ww), W1);
  return b;
}

// K0: init bbox to {H, -1, W, -1} (ws is poisoned 0xAA before each call)
__global__ void k_init(int* __restrict__ bbox) {
  bbox[0] = Hh; bbox[1] = -1; bbox[2] = Ww; bbox[3] = -1;
}

// K1: bounding box of changed pixels. grid = 1024 x 256 covers H*W exactly.
__global__ __launch_bounds__(256) void k_bbox(const float* __restrict__ x,
                                              const float* __restrict__ xp,
                                              int* __restrict__ bbox) {
  int idx = blockIdx.x * 256 + threadIdx.x;      // 0 .. 262143
  int h = idx >> 9, w = idx & 511;
  bool d = false;
#pragma unroll
  for (int c = 0; c < CIN; ++c)
    d |= (x[c * Hh * Ww + idx] != xp[c * Hh * Ww + idx]);
  int hmin = d ? h : 0x7FFFFFFF;
  int hmax = d ? h : -1;
  int wmin = d ? w : 0x7FFFFFFF;
  int wmax = d ? w : -1;
#pragma unroll
  for (int off = 32; off > 0; off >>= 1) {
    hmin = min(hmin, __shfl_down(hmin, off, 64));
    hmax = max(hmax, __shfl_down(hmax, off, 64));
    wmin = min(wmin, __shfl_down(wmin, off, 64));
    wmax = max(wmax, __shfl_down(wmax, off, 64));
  }
  if ((threadIdx.x & 63) == 0 && hmax >= 0) {
    atomicMin(&bbox[0], hmin);
    atomicMax(&bbox[1], hmax);
    atomicMin(&bbox[2], wmin);
    atomicMax(&bbox[3], wmax);
  }
}

// K2: blended c1 on the conv2-input region [bx1,bx2) x [by1,by2)
__global__ __launch_bounds__(256) void k_c1(const float* __restrict__ x,
                                            const float* __restrict__ w1,
                                            const float* __restrict__ b1,
                                            const float* __restrict__ lc1,
                                            const int* __restrict__ bbox,
                                            float* __restrict__ c1buf) {
  Box b = make_box(bbox);
  int R1h = b.bx2 - b.bx1, R1w = b.by2 - b.by1;
  if (R1h <= 0 || R1w <= 0) return;
  int total = C1C * R1h * R1w;
  int m1r1 = b.rx2 - 2, m1c1 = b.ry2 - 2;
  int stride = gridDim.x * blockDim.x;
  for (int e = blockIdx.x * blockDim.x + threadIdx.x; e < total; e += stride) {
    int c = e / (R1h * R1w);
    int rem = e - c * (R1h * R1w);
    int ri = rem / R1w;
    int rj = rem - ri * R1w;
    int i = b.bx1 + ri, j = b.by1 + rj;
    float val;
    if (i >= b.rx1 && i < m1r1 && j >= b.ry1 && j < m1c1) {
      float s = b1[c];
#pragma unroll
      for (int ic = 0; ic < CIN; ++ic)
#pragma unroll
        for (int kh = 0; kh < 3; ++kh)
#pragma unroll
          for (int kw = 0; kw < 3; ++kw)
            s = fmaf(x[(ic * Hh + i + kh) * Ww + j + kw],
                     w1[((c * CIN + ic) * 3 + kh) * 3 + kw], s);
      val = fmaxf(s, 0.f);
    } else {
      val = lc1[(c * H1 + i) * W1 + j];
    }
    c1buf[e] = val;
  }
}

// K3: c2 delta (relu(conv2(c1)) - last_c2) on mask2 region
__global__ __launch_bounds__(256) void k_c2(const float* __restrict__ c1buf,
                                            const float* __restrict__ w2,
                                            const float* __restrict__ b2,
                                            const float* __restrict__ lc2,
                                            const int* __restrict__ bbox,
                                            float* __restrict__ delta) {
  Box b = make_box(bbox);
  int R1h = b.bx2 - b.bx1, R1w = b.by2 - b.by1;
  int R2h = R1h - 2, R2w = R1w - 2;
  if (R2h <= 0 || R2w <= 0) return;
  int total = C2C * R2h * R2w;
  int stride = gridDim.x * blockDim.x;
  for (int e = blockIdx.x * blockDim.x + threadIdx.x; e < total; e += stride) {
    int oc = e / (R2h * R2w);
    int rem = e - oc * (R2h * R2w);
    int ri = rem / R2w;
    int rj = rem - ri * R2w;
    int i2 = b.bx1 + ri, j2 = b.by1 + rj;
    float s = b2[oc];
#pragma unroll 4
    for (int ic = 0; ic < C1C; ++ic)
#pragma unroll
      for (int kh = 0; kh < 3; ++kh)
#pragma unroll
        for (int kw = 0; kw < 3; ++kw)
          s = fmaf(c1buf[(ic * R1h + ri + kh) * R1w + rj + kw],
                   w2[((oc * C1C + ic) * 3 + kh) * 3 + kw], s);
    float val = fmaxf(s, 0.f);
    delta[e] = val - lc2[(oc * H2 + i2) * W2 + j2];
  }
}

// Per-block reduce of acc[NACT] -> partial[bid][NACT]
__device__ inline void block_reduce_store(float* acc, float* __restrict__ partial) {
#pragma unroll
  for (int a = 0; a < NACT; ++a)
#pragma unroll
    for (int off = 32; off > 0; off >>= 1)
      acc[a] += __shfl_down(acc[a], off, 64);
  __shared__ float red[4][NACT];
  int lane = threadIdx.x & 63, wid = threadIdx.x >> 6;
  if (lane == 0) {
#pragma unroll
    for (int a = 0; a < NACT; ++a) red[wid][a] = acc[a];
  }
  __syncthreads();
  if (threadIdx.x < NACT) {
    float s = red[0][threadIdx.x] + red[1][threadIdx.x] +
              red[2][threadIdx.x] + red[3][threadIdx.x];
    partial[blockIdx.x * NACT + threadIdx.x] = s;
  }
}

// K4: base MV  partial1[blk][a] = sum_cols fc_w[a,col] * last_c2[col]
__global__ __launch_bounds__(256) void k_mv(const float4* __restrict__ fcw,
                                            const float4* __restrict__ vec,
                                            float* __restrict__ partial1) {
  float acc[NACT];
#pragma unroll
  for (int a = 0; a < NACT; ++a) acc[a] = 0.f;
  int stride = gridDim.x * blockDim.x;
  for (int col = blockIdx.x * blockDim.x + threadIdx.x; col < N4; col += stride) {
    float4 v = vec[col];
#pragma unroll
    for (int a = 0; a < NACT; ++a) {
      float4 w = fcw[(size_t)a * N4 + col];
      acc[a] += w.x * v.x + w.y * v.y + w.z * v.z + w.w * v.w;
    }
  }
  block_reduce_store(acc, partial1);
}

// K5: correction  partial2[blk][a] = sum_region fc_w[a, gidx] * delta
__global__ __launch_bounds__(256) void k_corr(const float* __restrict__ fcw,
                                              const float* __restrict__ delta,
                                              const int* __restrict__ bbox,
                                              float* __restrict__ partial2) {
  Box b = make_box(bbox);
  int R1h = b.bx2 - b.bx1, R1w = b.by2 - b.by1;
  int R2h = R1h - 2, R2w = R1w - 2;
  int total = (R2h > 0 && R2w > 0) ? C2C * R2h * R2w : 0;
  float acc[NACT];
#pragma unroll
  for (int a = 0; a < NACT; ++a) acc[a] = 0.f;
  int stride = gridDim.x * blockDim.x;
  for (int e = blockIdx.x * blockDim.x + threadIdx.x; e < total; e += stride) {
    int oc = e / (R2h * R2w);
    int rem = e - oc * (R2h * R2w);
    int ri = rem / R2w;
    int rj = rem - ri * R2w;
    int gidx = (oc * H2 + b.bx1 + ri) * W2 + b.by1 + rj;
    float d = delta[e];
#pragma unroll
    for (int a = 0; a < NACT; ++a)
      acc[a] = fmaf(fcw[(size_t)a * NFC + gidx], d, acc[a]);
  }
  block_reduce_store(acc, partial2);
}

// K6: reduce partials, softmax, write 18 outputs
__global__ __launch_bounds__(1024) void k_final(const float* __restrict__ partial1,
                                                const float* __restrict__ partial2,
                                                float* __restrict__ out) {
  __shared__ float red[1024];
  __shared__ float logits[NACT];
  int t = threadIdx.x;
  float s = 0.f;
  const int NG = 1024 / NACT;               // 56 groups of 18
  if (t < NG * NACT) {
    int a = t % NACT, g = t / NACT;
    for (int bi = g; bi < GRID_MV; bi += NG)   s += partial1[bi * NACT + a];
    for (int bi = g; bi < GRID_CORR; bi += NG) s += partial2[bi * NACT + a];
  }
  red[t] = s;
  __syncthreads();
  if (t < NACT) {
    float tot = 0.f;
    for (int g = 0; g < NG; ++g) tot += red[g * NACT + t];
    logits[t] = tot;
  }
  __syncthreads();
  if (t == 0) {
    float mx = -FLT_MAX;
#pragma unroll
    for (int a = 0; a < NACT; ++a) mx = fmaxf(mx, logits[a]);
    float se = 0.f;
    float e[NACT];
#pragma unroll
    for (int a = 0; a < NACT; ++a) { e[a] = expf(logits[a] - mx); se += e[a]; }
    float inv = 1.f / se;
#pragma unroll
    for (int a = 0; a < NACT; ++a) out[a] = e[a] * inv;
  }
}

extern "C" void kernel_launch(void* const* d_in, const int* in_sizes, int n_in,
                              void* d_out, int out_size, void* d_ws, size_t ws_size,
                              hipStream_t stream) {
  const float* x   = (const float*)d_in[0];
  const float* xp  = (const float*)d_in[1];
  const float* lc1 = (const float*)d_in[2];
  const float* lc2 = (const float*)d_in[3];
  const float* w1  = (const float*)d_in[4];
  const float* b1  = (const float*)d_in[5];
  const float* w2  = (const float*)d_in[6];
  const float* b2  = (const float*)d_in[7];
  const float* fcw = (const float*)d_in[8];
  float* out = (float*)d_out;

  char* ws = (char*)d_ws;
  int*   bbox     = (int*)ws;
  float* partial1 = (float*)(ws + 1024);                       // 2048*18*4 = 147456 B
  float* partial2 = (float*)(ws + 1024 + 147456);              // 256*18*4  = 18432 B
  // region buffers: compact by default; generous if ws is large (general safety)
  size_t off_c1 = 262144, off_dl = 1048576;
  if (ws_size >= ((size_t)96 << 20)) { off_c1 = (size_t)8 << 20; off_dl = (size_t)40 << 20; }
  float* c1buf = (float*)(ws + off_c1);
  float* delta = (float*)(ws + off_dl);

  k_init<<<1, 1, 0, stream>>>(bbox);
  k_bbox<<<1024, 256, 0, stream>>>(x, xp, bbox);
  k_c1<<<64, 256, 0, stream>>>(x, w1, b1, lc1, bbox, c1buf);
  k_c2<<<128, 256, 0, stream>>>(c1buf, w2, b2, lc2, bbox, delta);
  k_mv<<<GRID_MV, 256, 0, stream>>>((const float4*)fcw, (const float4*)lc2, partial1);
  k_corr<<<GRID_CORR, 256, 0, stream>>>(fcw, delta, bbox, partial2);
  k_final<<<1, 1024, 0, stream>>>(partial1, partial2, out);
}

// Round 8
// 1028.435 us; speedup vs baseline: 1.0299x; 1.0299x over previous
//
#include <hip/hip_runtime.h>
#include <cfloat>
#include <climits>

// Problem constants (match reference)
#define Hh 512
#define Ww 512
#define H1 510
#define W1 510
#define H2 508
#define W2 508
#define CIN 3
#define C1C 20
#define C2C 40
#define NACT 18
#define NFC (C2C * H2 * W2)      // 10,322,560
#define N4  (NFC / 4)            // 2,580,640 float4

#define GRID_MV   2048
#define GRID_C2   256

typedef float f32x4 __attribute__((ext_vector_type(4)));

// ---------------- bbox helpers ----------------
struct Box { int rx1, rx2, ry1, ry2, bx1, bx2, by1, by2; };

__device__ inline Box make_box(const int* __restrict__ bb) {
  Box b;
  int mnx = bb[0], mxx = bb[1], mny = bb[2], mxy = bb[3];
  b.rx1 = max(mnx - 2, 0);  b.rx2 = min(mxx + 3, Hh);
  b.ry1 = max(mny - 2, 0);  b.ry2 = min(mxy + 3, Ww);
  b.bx1 = max(b.rx1 - 2, 0); b.bx2 = min(min(b.rx2 + 3, Hh), H1);
  b.by1 = max(b.ry1 - 2, 0); b.by2 = min(min(b.ry2 + 3, Ww), W1);
  return b;
}

// K0: init bbox sentinels (ws is poisoned 0xAA -> must init before atomics)
__global__ void k_init(int* __restrict__ bbox) {
  bbox[0] = Hh; bbox[1] = -1; bbox[2] = Ww; bbox[3] = -1;
}

// K1: bbox of changed pixels; float4 loads, 256 blocks x 256 thr covers H*W/4.
__global__ __launch_bounds__(256) void k_bbox(const f32x4* __restrict__ x4,
                                              const f32x4* __restrict__ xp4,
                                              int* __restrict__ bbox) {
  int q = blockIdx.x * 256 + threadIdx.x;        // 0..65535, 4 pixels each
  int h = q >> 7, w0 = (q & 127) << 2;           // row, first col of the 4
  unsigned dm = 0;
#pragma unroll
  for (int c = 0; c < CIN; ++c) {
    f32x4 a = x4[c * 65536 + q], b = xp4[c * 65536 + q];
    dm |= (a.x != b.x) ? 1u : 0u;
    dm |= (a.y != b.y) ? 2u : 0u;
    dm |= (a.z != b.z) ? 4u : 0u;
    dm |= (a.w != b.w) ? 8u : 0u;
  }
  int hmin = dm ? h : INT_MAX, hmax = dm ? h : -1;
  int wmin = INT_MAX, wmax = -1;
  if (dm) {
    wmin = w0 + (__ffs(dm) - 1);
    wmax = w0 + (31 - __clz(dm));
  }
#pragma unroll
  for (int off = 32; off > 0; off >>= 1) {
    hmin = min(hmin, __shfl_down(hmin, off, 64));
    hmax = max(hmax, __shfl_down(hmax, off, 64));
    wmin = min(wmin, __shfl_down(wmin, off, 64));
    wmax = max(wmax, __shfl_down(wmax, off, 64));
  }
  if ((threadIdx.x & 63) == 0 && hmax >= 0) {
    atomicMin(&bbox[0], hmin);
    atomicMax(&bbox[1], hmax);
    atomicMin(&bbox[2], wmin);
    atomicMax(&bbox[3], wmax);
  }
}

// K2: blended c1 on the conv2-input region [bx1,bx2) x [by1,by2)
__global__ __launch_bounds__(256) void k_c1(const float* __restrict__ x,
                                            const float* __restrict__ w1,
                                            const float* __restrict__ b1,
                                            const float* __restrict__ lc1,
                                            const int* __restrict__ bbox,
                                            float* __restrict__ c1buf) {
  Box b = make_box(bbox);
  int R1h = b.bx2 - b.bx1, R1w = b.by2 - b.by1;
  if (R1h <= 0 || R1w <= 0) return;
  int total = C1C * R1h * R1w;
  int m1r1 = b.rx2 - 2, m1c1 = b.ry2 - 2;
  int stride = gridDim.x * blockDim.x;
  for (int e = blockIdx.x * blockDim.x + threadIdx.x; e < total; e += stride) {
    int c = e / (R1h * R1w);
    int rem = e - c * (R1h * R1w);
    int ri = rem / R1w;
    int rj = rem - ri * R1w;
    int i = b.bx1 + ri, j = b.by1 + rj;
    float val;
    if (i >= b.rx1 && i < m1r1 && j >= b.ry1 && j < m1c1) {
      float s = b1[c];
#pragma unroll
      for (int ic = 0; ic < CIN; ++ic)
#pragma unroll
        for (int kh = 0; kh < 3; ++kh)
#pragma unroll
          for (int kw = 0; kw < 3; ++kw)
            s = fmaf(x[(ic * Hh + i + kh) * Ww + j + kw],
                     w1[((c * CIN + ic) * 3 + kh) * 3 + kw], s);
      val = fmaxf(s, 0.f);
    } else {
      val = lc1[(c * H1 + i) * W1 + j];
    }
    c1buf[e] = val;
  }
}

// Per-block reduce of acc[NACT] -> partial[bid][NACT] (unconditional write)
__device__ inline void block_reduce_store(float* acc, float* __restrict__ partial) {
#pragma unroll
  for (int a = 0; a < NACT; ++a)
#pragma unroll
    for (int off = 32; off > 0; off >>= 1)
      acc[a] += __shfl_down(acc[a], off, 64);
  __shared__ float red[4][NACT];
  int lane = threadIdx.x & 63, wid = threadIdx.x >> 6;
  if (lane == 0) {
#pragma unroll
    for (int a = 0; a < NACT; ++a) red[wid][a] = acc[a];
  }
  __syncthreads();
  if (threadIdx.x < NACT) {
    float s = red[0][threadIdx.x] + red[1][threadIdx.x] +
              red[2][threadIdx.x] + red[3][threadIdx.x];
    partial[blockIdx.x * NACT + threadIdx.x] = s;
  }
}

// K3: fused c2-delta + FC correction:
// partial2[blk][a] = sum_{mask2 region} fc_w[a, gidx] * (relu(conv2(c1))-last_c2)
__global__ __launch_bounds__(256) void k_c2corr(const float* __restrict__ c1buf,
                                                const float* __restrict__ w2,
                                                const float* __restrict__ b2,
                                                const float* __restrict__ lc2,
                                                const float* __restrict__ fcw,
                                                const int* __restrict__ bbox,
                                                float* __restrict__ partial2) {
  Box b = make_box(bbox);
  int R1h = b.bx2 - b.bx1, R1w = b.by2 - b.by1;
  int R2h = R1h - 2, R2w = R1w - 2;
  int total = (R2h > 0 && R2w > 0) ? C2C * R2h * R2w : 0;
  float acc[NACT];
#pragma unroll
  for (int a = 0; a < NACT; ++a) acc[a] = 0.f;
  int stride = gridDim.x * blockDim.x;
  for (int e = blockIdx.x * blockDim.x + threadIdx.x; e < total; e += stride) {
    int oc = e / (R2h * R2w);
    int rem = e - oc * (R2h * R2w);
    int ri = rem / R2w;
    int rj = rem - ri * R2w;
    float s = b2[oc];
#pragma unroll 4
    for (int ic = 0; ic < C1C; ++ic)
#pragma unroll
      for (int kh = 0; kh < 3; ++kh)
#pragma unroll
        for (int kw = 0; kw < 3; ++kw)
          s = fmaf(c1buf[(ic * R1h + ri + kh) * R1w + rj + kw],
                   w2[((oc * C1C + ic) * 3 + kh) * 3 + kw], s);
    int gidx = (oc * H2 + b.bx1 + ri) * W2 + b.by1 + rj;
    float d = fmaxf(s, 0.f) - lc2[gidx];
#pragma unroll
    for (int a = 0; a < NACT; ++a)
      acc[a] = fmaf(fcw[(size_t)a * NFC + gidx], d, acc[a]);
  }
  block_reduce_store(acc, partial2);
}

// K4: base MV  partial1[blk][a] = sum_cols fc_w[a,col] * last_c2[col]
// Block-contiguous column chunks; nontemporal loads on the 743 MB fcw stream.
__global__ __launch_bounds__(256) void k_mv(const f32x4* __restrict__ fcw,
                                            const f32x4* __restrict__ vec,
                                            float* __restrict__ partial1) {
  const int CHUNK = (N4 + GRID_MV - 1) / GRID_MV;   // 1261
  int start = blockIdx.x * CHUNK;
  int end = min(start + CHUNK, N4);
  float acc[NACT];
#pragma unroll
  for (int a = 0; a < NACT; ++a) acc[a] = 0.f;
  for (int col = start + threadIdx.x; col < end; col += 256) {
    f32x4 v = vec[col];
#pragma unroll
    for (int a = 0; a < NACT; ++a) {
      f32x4 w = __builtin_nontemporal_load(&fcw[(size_t)a * N4 + col]);
      acc[a] += w.x * v.x + w.y * v.y + w.z * v.z + w.w * v.w;
    }
  }
  block_reduce_store(acc, partial1);
}

// K5: reduce partials, softmax, write 18 outputs
__global__ __launch_bounds__(1024) void k_final(const float* __restrict__ partial1,
                                                const float* __restrict__ partial2,
                                                float* __restrict__ out) {
  __shared__ float red[1024];
  __shared__ float logits[NACT];
  int t = threadIdx.x;
  float s = 0.f;
  const int NG = 1024 / NACT;               // 56 groups of 18
  if (t < NG * NACT) {
    int a = t % NACT, g = t / NACT;
    for (int bi = g; bi < GRID_MV; bi += NG) s += partial1[bi * NACT + a];
    for (int bi = g; bi < GRID_C2; bi += NG) s += partial2[bi * NACT + a];
  }
  red[t] = s;
  __syncthreads();
  if (t < NACT) {
    float tot = 0.f;
    for (int g = 0; g < NG; ++g) tot += red[g * NACT + t];
    logits[t] = tot;
  }
  __syncthreads();
  if (t == 0) {
    float mx = -FLT_MAX;
#pragma unroll
    for (int a = 0; a < NACT; ++a) mx = fmaxf(mx, logits[a]);
    float se = 0.f;
    float e[NACT];
#pragma unroll
    for (int a = 0; a < NACT; ++a) { e[a] = expf(logits[a] - mx); se += e[a]; }
    float inv = 1.f / se;
#pragma unroll
    for (int a = 0; a < NACT; ++a) out[a] = e[a] * inv;
  }
}

extern "C" void kernel_launch(void* const* d_in, const int* in_sizes, int n_in,
                              void* d_out, int out_size, void* d_ws, size_t ws_size,
                              hipStream_t stream) {
  const float* x   = (const float*)d_in[0];
  const float* xp  = (const float*)d_in[1];
  const float* lc1 = (const float*)d_in[2];
  const float* lc2 = (const float*)d_in[3];
  const float* w1  = (const float*)d_in[4];
  const float* b1  = (const float*)d_in[5];
  const float* w2  = (const float*)d_in[6];
  const float* b2  = (const float*)d_in[7];
  const float* fcw = (const float*)d_in[8];
  float* out = (float*)d_out;

  char* ws = (char*)d_ws;
  int*   bbox     = (int*)ws;                          // 16 B
  float* partial1 = (float*)(ws + 4096);               // 2048*18*4 = 147456 B
  float* partial2 = (float*)(ws + 4096 + 147456);      // 256*18*4  = 18432 B
  float* c1buf    = (float*)(ws + (1u << 20));         // worst case 20.8 MB

  // k_mv first: it is the long pole and depends only on inputs.
  k_mv<<<GRID_MV, 256, 0, stream>>>((const f32x4*)fcw, (const f32x4*)lc2, partial1);
  k_init<<<1, 1, 0, stream>>>(bbox);
  k_bbox<<<256, 256, 0, stream>>>((const f32x4*)x, (const f32x4*)xp, bbox);
  k_c1<<<64, 256, 0, stream>>>(x, w1, b1, lc1, bbox, c1buf);
  k_c2corr<<<GRID_C2, 256, 0, stream>>>(c1buf, w2, b2, lc2, fcw, bbox, partial2);
  k_final<<<1, 1024, 0, stream>>>(partial1, partial2, out);
}